// Round 10
// baseline (124.253 us; speedup 1.0000x reference)
//
#include <hip/hip_runtime.h>

#define N_PTS 8192
#define D_DIM 256
#define BN 256              // set1 rows per block
#define BM 128              // set2 rows per block
#define BK 64               // k-elems per stage (64 fp8 = 64 B/row = 4 x 16B chunks)
#define NBLK ((N_PTS / BN) * (N_PTS / BM))   // 2048
#define INF_BITS 0x7F800000u

typedef __attribute__((ext_vector_type(4))) float f32x4;

// async global->LDS, 16B/lane; LDS dest = wave-uniform base + lane*16
__device__ __forceinline__ void gload_lds16(const unsigned char* g, unsigned char* l) {
    __builtin_amdgcn_global_load_lds(
        (const __attribute__((address_space(1))) void*)g,
        (__attribute__((address_space(3))) void*)l, 16, 0, 0);
}

// ---- fused prep: fp8 e4m3 convert + row sqnorms (fp32 exact) + INF init + counter=0 ----
__global__ void prep_kernel(const float* __restrict__ s1, const float* __restrict__ s2,
                            unsigned char* __restrict__ f1, unsigned char* __restrict__ f2,
                            float* __restrict__ sq1, float* __restrict__ sq2,
                            unsigned* __restrict__ rowmin2, unsigned* __restrict__ colmin2,
                            unsigned* __restrict__ counter) {
    const int half = N_PTS * D_DIM;
    int t = blockIdx.x * 256 + threadIdx.x;
    int e = t * 8;
    bool first = e < half;
    const float* src = first ? s1 : s2;
    unsigned char* dst = first ? f1 : f2;
    int off = first ? e : e - half;
    float4 v0 = *(const float4*)(src + off);
    float4 v1 = *(const float4*)(src + off + 4);
    float s = v0.x * v0.x + v0.y * v0.y + v0.z * v0.z + v0.w * v0.w
            + v1.x * v1.x + v1.y * v1.y + v1.z * v1.z + v1.w * v1.w;
    // OCP e4m3 pack: N(0,1) inputs are far from the ±448 sat range
    int p0 = __builtin_amdgcn_cvt_pk_fp8_f32(v0.x, v0.y, 0, false);
    p0     = __builtin_amdgcn_cvt_pk_fp8_f32(v0.z, v0.w, p0, true);
    int p1 = __builtin_amdgcn_cvt_pk_fp8_f32(v1.x, v1.y, 0, false);
    p1     = __builtin_amdgcn_cvt_pk_fp8_f32(v1.z, v1.w, p1, true);
    *(int2*)(dst + off) = make_int2(p0, p1);
    // one row = 32 consecutive threads; xor masks <=16 stay inside the half-wave
    #pragma unroll
    for (int m = 1; m <= 16; m <<= 1) s += __shfl_xor(s, m, 64);
    int sub = threadIdx.x & 31;
    int row = off >> 8;
    if (sub == 0) (first ? sq1 : sq2)[row] = s;
    if (sub == 1) (first ? rowmin2 : colmin2)[row] = INF_BITS;
    if (t == 0) *counter = 0;
}

// ---- fp8 MFMA gram + fused d^2 + min + fenceless last-block reduce ----
__global__ __launch_bounds__(256, 3) void tile_kernel(
    const unsigned char* __restrict__ F1, const unsigned char* __restrict__ F2,
    const float* __restrict__ sq1, const float* __restrict__ sq2,
    unsigned* __restrict__ rowmin2, unsigned* __restrict__ colmin2,
    unsigned* __restrict__ counter, float* __restrict__ out) {
    // unpadded row-major [rows][64B] fp8, XOR-swizzled in 16B chunks:
    // LDS slot (row, sc) holds global chunk (row, sc ^ ((row>>1)&3)).
    // Fragment b64 reads then land 2-way per bank-pair -> uniform 4/bank for
    // the full wave64 (optimal for 8B/lane). Coupled to the 16x16 read shape.
    __shared__ unsigned char As[BN * BK] __attribute__((aligned(16)));   // 16 KB
    __shared__ unsigned char Bs[BM * BK] __attribute__((aligned(16)));   //  8 KB
    __shared__ unsigned rs[BN];
    __shared__ unsigned cs[BM];
    __shared__ unsigned s_old;
    __shared__ float wsum[4];

    const int tid  = threadIdx.x;
    const int lane = tid & 63;
    const int w    = tid >> 6;
    const int quad = lane >> 4;
    const int c    = lane & 15;
    const int n_off = (w >> 1) * 128;   // wave tile: 128(n) x 64(m)
    const int m_off = (w & 1) * 64;
    const int n0 = blockIdx.y * BN;
    const int m0 = blockIdx.x * BM;

    rs[tid] = INF_BITS;
    if (tid < BM) cs[tid] = INF_BITS;

    f32x4 acc[8][4];
    #pragma unroll
    for (int ti = 0; ti < 8; ti++)
        #pragma unroll
        for (int tj = 0; tj < 4; tj++) acc[ti][tj] = (f32x4){0.f, 0.f, 0.f, 0.f};

    for (int k0 = 0; k0 < D_DIM; k0 += BK) {
        // stage As: 256 rows x 4 chunks = 1024 chunks, 4 rounds of 256
        #pragma unroll
        for (int r = 0; r < 4; r++) {
            int idx = r * 256 + tid;
            int row = idx >> 2;
            int gc  = (idx & 3) ^ ((row >> 1) & 3);
            gload_lds16(F1 + (size_t)(n0 + row) * D_DIM + k0 + gc * 16,
                        &As[(idx & ~63) * 16]);
        }
        // stage Bs: 128 rows x 4 chunks = 512 chunks, 2 rounds
        #pragma unroll
        for (int r = 0; r < 2; r++) {
            int idx = r * 256 + tid;
            int row = idx >> 2;
            int gc  = (idx & 3) ^ ((row >> 1) & 3);
            gload_lds16(F2 + (size_t)(m0 + row) * D_DIM + k0 + gc * 16,
                        &Bs[(idx & ~63) * 16]);
        }
        __syncthreads();

        // lane (quad q, col c): A[row = tile+c][k = kk*32 + q*8 .. +7] (8 B)
        #pragma unroll
        for (int kk = 0; kk < 2; kk++) {
            long a[8], b[4];
            #pragma unroll
            for (int ti = 0; ti < 8; ti++) {
                int row  = n_off + ti * 16 + c;
                int slot = (kk * 2 + (quad >> 1)) ^ ((row >> 1) & 3);
                a[ti] = *(const long*)&As[row * BK + slot * 16 + (quad & 1) * 8];
            }
            #pragma unroll
            for (int tj = 0; tj < 4; tj++) {
                int row  = m_off + tj * 16 + c;
                int slot = (kk * 2 + (quad >> 1)) ^ ((row >> 1) & 3);
                b[tj] = *(const long*)&Bs[row * BK + slot * 16 + (quad & 1) * 8];
            }
            #pragma unroll
            for (int ti = 0; ti < 8; ti++)
                #pragma unroll
                for (int tj = 0; tj < 4; tj++)
                    acc[ti][tj] = __builtin_amdgcn_mfma_f32_16x16x32_fp8_fp8(
                        a[ti], b[tj], acc[ti][tj], 0, 0, 0);
        }
        __syncthreads();
    }

    // epilogue: d2 = sq1[n]+sq2[m]-2*gram; C/D: col(m)=lane&15, row(n)=quad*4+reg
    float sqm[4];
    #pragma unroll
    for (int tj = 0; tj < 4; tj++) sqm[tj] = sq2[m0 + m_off + tj * 16 + c];
    float cmin[4];
    #pragma unroll
    for (int tj = 0; tj < 4; tj++) cmin[tj] = __uint_as_float(INF_BITS);

    #pragma unroll
    for (int ti = 0; ti < 8; ti++) {
        float4 sqn = *(const float4*)&sq1[n0 + n_off + ti * 16 + quad * 4];
        float snr[4] = { sqn.x, sqn.y, sqn.z, sqn.w };
        float rmin[4] = { __uint_as_float(INF_BITS), __uint_as_float(INF_BITS),
                          __uint_as_float(INF_BITS), __uint_as_float(INF_BITS) };
        #pragma unroll
        for (int tj = 0; tj < 4; tj++)
            #pragma unroll
            for (int r = 0; r < 4; r++) {
                float d2 = fmaxf(snr[r] + sqm[tj] - 2.f * acc[ti][tj][r], 0.f);
                rmin[r]  = fminf(rmin[r], d2);
                cmin[tj] = fminf(cmin[tj], d2);
            }
        #pragma unroll
        for (int m = 1; m <= 8; m <<= 1)
            #pragma unroll
            for (int r = 0; r < 4; r++)
                rmin[r] = fminf(rmin[r], __shfl_xor(rmin[r], m, 64));
        if (c == 0) {
            #pragma unroll
            for (int r = 0; r < 4; r++)
                atomicMin(&rs[n_off + ti * 16 + quad * 4 + r], __float_as_uint(rmin[r]));
        }
    }
    #pragma unroll
    for (int m = 16; m <= 32; m <<= 1)
        #pragma unroll
        for (int tj = 0; tj < 4; tj++)
            cmin[tj] = fminf(cmin[tj], __shfl_xor(cmin[tj], m, 64));
    if (quad == 0) {
        #pragma unroll
        for (int tj = 0; tj < 4; tj++)
            atomicMin(&cs[m_off + tj * 16 + c], __float_as_uint(cmin[tj]));
    }
    __syncthreads();

    atomicMin(&rowmin2[n0 + tid], rs[tid]);          // BN == 256 == blockDim
    if (tid < BM) atomicMin(&colmin2[m0 + tid], cs[tid]);

    // ---- fenceless last-block reduction (verified R7/R8/R9) ----
    __syncthreads();   // per-wave s_waitcnt vmcnt(0): our device-scope atomicMins are acked
    if (tid == 0)
        s_old = __hip_atomic_fetch_add(counter, 1u, __ATOMIC_RELAXED,
                                       __HIP_MEMORY_SCOPE_AGENT);
    __syncthreads();
    if (s_old == NBLK - 1) {
        const unsigned* mins = rowmin2;              // rowmin2||colmin2: 16384 uints
        float s = 0.f;
        #pragma unroll 1
        for (int j = 0; j < 64; j += 8) {
            unsigned v[8];
            #pragma unroll
            for (int q = 0; q < 8; q++)
                v[q] = __hip_atomic_load(&mins[(j + q) * 256 + tid],
                                         __ATOMIC_RELAXED, __HIP_MEMORY_SCOPE_AGENT);
            #pragma unroll
            for (int q = 0; q < 8; q++) s += sqrtf(__uint_as_float(v[q]));
        }
        #pragma unroll
        for (int m = 32; m > 0; m >>= 1) s += __shfl_xor(s, m, 64);
        if (lane == 0) wsum[w] = s;
        __syncthreads();
        if (tid == 0) out[0] = (wsum[0] + wsum[1] + wsum[2] + wsum[3]) / (float)N_PTS;
    }
}

extern "C" void kernel_launch(void* const* d_in, const int* in_sizes, int n_in,
                              void* d_out, int out_size, void* d_ws, size_t ws_size,
                              hipStream_t stream) {
    const float* set1 = (const float*)d_in[0];
    const float* set2 = (const float*)d_in[1];
    float* out = (float*)d_out;

    // workspace: rowmin2[8192] | colmin2[8192] (contiguous!) | sq1 | sq2 | counter | f1 | f2
    unsigned* rowmin2 = (unsigned*)d_ws;
    unsigned* colmin2 = rowmin2 + N_PTS;
    float* sq1 = (float*)(colmin2 + N_PTS);
    float* sq2 = sq1 + N_PTS;
    unsigned* counter = (unsigned*)(sq2 + N_PTS);
    unsigned char* f1 = (unsigned char*)d_ws + 128 * 1024;   // past headers, 256B-aligned
    unsigned char* f2 = f1 + (size_t)N_PTS * D_DIM;

    prep_kernel<<<(2 * N_PTS * D_DIM) / (256 * 8), 256, 0, stream>>>(
        set1, set2, f1, f2, sq1, sq2, rowmin2, colmin2, counter);
    tile_kernel<<<dim3(N_PTS / BM, N_PTS / BN), 256, 0, stream>>>(
        f1, f2, sq1, sq2, rowmin2, colmin2, counter, out);
}